// Round 13
// baseline (470.258 us; speedup 1.0000x reference)
//
#include <hip/hip_runtime.h>

// ---------------- problem constants ----------------
#define F_BINS 257
#define NCH    8
#define NSRC   2
#define KW     5
#define HCH    32
#define TLEN   2000
#define BATCH  4

// ---------------- tiling ----------------
#define TT      128
#define NTILES  16          // 16*128 = 2048 >= 2000
#define TPB     2           // tiles per block (pipelined)
#define NTG2    (NTILES / TPB)          // 8 tile-groups
#define NK      (BATCH * F_BINS)        // 1028 (b,f) pairs
#define NRANK   ((NK + 7) / 8)          // 129
#define GRID    (NRANK * NTG2 * 8)      // 8256 (few dead blocks)

// LDS layout (bytes). X double-buffered; h3 aliases H1.
#define XSTRIDE 24
#define XCOLS   148
#define XSZ     (XCOLS * XSTRIDE * 2)          // 7104 B
#define X0OFF   0
#define X1OFF   XSZ                            // 7104
#define HWIN    144                            // h1/h2 window: [t0-8, t0+136)
#define HSZ     (HWIN * 64 * 2)                // 18432 B
#define H1OFF   (2 * XSZ)                      // 14208
#define H2OFF   (H1OFF + HSZ)                  // 32640
#define SMEM_BYTES (H2OFF + HSZ)               // 51072 B -> 3 blocks/CU (153KB/160KB)
#define H3OFF   H1OFF                          // h3 aliases h1 (dead after L2)
#define H3STRIDE 40                            // halves per col (32 used + pad)

// packed weight fragments: [f][frag*2+mw][lane] of half8 (16B each)
#define NFRAG   36
#define PW_HALF8_PER_F (NFRAG * 2 * 64)
#define PW_BYTES ((size_t)F_BINS * PW_HALF8_PER_F * 16)   // ~18.9 MB

typedef _Float16 half8  __attribute__((ext_vector_type(8)));
typedef __fp16   pk16x2 __attribute__((ext_vector_type(2)));   // cvt_pkrtz result type
typedef __fp16   pk16x4 __attribute__((ext_vector_type(4)));   // merged 8B epi store
typedef float    f32x4  __attribute__((ext_vector_type(4)));

#define MFMA16(a, b, c) __builtin_amdgcn_mfma_f32_16x16x32_f16(a, b, c, 0, 0, 0)

// frag ids: a1[hr][p] = hr*3+p (0..5); a2[w][hr][kk] = 6+w*4+hr*2+kk (6..25);
//           a3[w][kk] = 26+w*2+kk (26..35)
__device__ __forceinline__ half8 gather_frag(
    int f, int frag, int mw, int lane,
    const float* __restrict__ Wr1, const float* __restrict__ Wi1,
    const float* __restrict__ Wr2, const float* __restrict__ Wi2,
    const float* __restrict__ Wr3, const float* __restrict__ Wi3)
{
    const int g = lane >> 4, r16 = lane & 15;
    half8 v;
    if (frag < 6) {
        int hr = frag / 3, p = frag % 3;
        int tap = 2 * p + (g >> 1);
        #pragma unroll
        for (int j = 0; j < 8; ++j) {
            float val = 0.f;
            if (tap < KW) {
                long idx = (((long)f * HCH + hr * 16 + r16) * NCH + j) * KW + tap;
                if (mw == 0) val = (g & 1) ? -Wi1[idx] : Wr1[idx];
                else         val = (g & 1) ?  Wr1[idx] : Wi1[idx];
            }
            v[j] = (_Float16)val;
        }
    } else if (frag < 26) {
        int u = frag - 6;
        int w = u >> 2, hr = (u >> 1) & 1, kk = u & 1;
        #pragma unroll
        for (int j = 0; j < 8; ++j) {
            int c = g * 8 + j;
            long idx = (((long)f * HCH + hr * 16 + r16) * HCH + c) * KW + w;
            float val;
            if (mw == 0) val = kk ? -Wi2[idx] : Wr2[idx];
            else         val = kk ?  Wr2[idx] : Wi2[idx];
            v[j] = (_Float16)val;
        }
    } else {
        int u = frag - 26;
        int w = u >> 1, kk = u & 1;
        #pragma unroll
        for (int j = 0; j < 8; ++j) {
            int c = g * 8 + j;
            long idx = (((long)f * (NCH * NSRC) + r16) * HCH + c) * KW + w;
            float val;
            if (mw == 0) val = kk ? -Wi3[idx] : Wr3[idx];
            else         val = kk ?  Wr3[idx] : Wi3[idx];
            v[j] = (_Float16)val;
        }
    }
    return v;
}

__global__ __launch_bounds__(256) void repack_kernel(
    const float* __restrict__ Wr1, const float* __restrict__ Wi1,
    const float* __restrict__ Wr2, const float* __restrict__ Wi2,
    const float* __restrict__ Wr3, const float* __restrict__ Wi3,
    _Float16* __restrict__ pw)
{
    const int bid  = blockIdx.x;
    const int f    = bid >> 2;
    const int part = bid & 3;
    const int lane = threadIdx.x & 63;
    const int q    = threadIdx.x >> 6;
    half8* pwv = (half8*)pw;
    for (int u = part * 18 + q; u < part * 18 + 18; u += 4) {
        int frag = u >> 1, mw = u & 1;
        half8 v = gather_frag(f, frag, mw, lane, Wr1, Wi1, Wr2, Wi2, Wr3, Wi3);
        pwv[((size_t)f * (NFRAG * 2) + u) * 64 + lane] = v;
    }
}

template<bool PACKED>
__global__ __launch_bounds__(256, 3) void cddcnn_mfma_kernel(
    const float* __restrict__ x,
    const float* __restrict__ Wr1, const float* __restrict__ Wi1,
    const float* __restrict__ Wr2, const float* __restrict__ Wi2,
    const float* __restrict__ Wr3, const float* __restrict__ Wi3,
    float* __restrict__ out, const _Float16* __restrict__ pw)
{
    __shared__ __align__(16) char sm[SMEM_BYTES];

    const int tid  = threadIdx.x;
    const int lane = tid & 63;
    const int wv   = tid >> 6;
    const int mw   = wv >> 1;       // 0: real-out rows, 1: imag-out rows
    const int nw   = wv & 1;        // n-half
    const int g    = lane >> 4;
    const int r16  = lane & 15;

    // XCD swizzle: the 8 tile-group blocks of one k=(b,f) all land on xcd=k&7,
    // so the per-f weight panel stays L2-resident (R12: FETCH 384->101 MB).
    const int bid  = blockIdx.x;
    const int xcd  = bid & 7;
    const int rest = bid >> 3;
    const int tg   = rest & 7;           // tile-group (tiles 2tg, 2tg+1)
    const int k    = ((rest >> 3) << 3) | xcd;
    if (k >= NK) return;
    const int f    = k % F_BINS;
    const int b    = k / F_BINS;

    const int nb0 = nw ? 5 : 0;
    const int nbn = nw ? 4 : 5;

    const half8* pwf = PACKED ? ((const half8*)pw) + (size_t)f * PW_HALF8_PER_F + mw * 64 + lane
                              : nullptr;
    #define LOADFRAG(fr) (PACKED ? pwf[(fr) * 128] \
                                 : gather_frag(f, (fr), mw, lane, Wr1, Wi1, Wr2, Wi2, Wr3, Wi3))

    const long xr_base = ((long)(b * 2 * F_BINS + f) * NCH) * TLEN;
    const long xi_base = ((long)(b * 2 * F_BINS + F_BINS + f) * NCH) * TLEN;

    // staging roles: threads 0..147 real half; threads 108..255 imag half.
    // Per role: 8 coalesced scalar loads -> 1x ds_write_b128 (conflict-free).
    const bool doR  = (tid < XCOLS);
    const bool doI  = (tid >= 256 - XCOLS);
    const int  colR = tid;
    const int  colI = tid - (256 - XCOLS);

    half8 pkr = {}, pki = {};

    // ---- prologue: issue tile-0 x loads FIRST (oldest in vmem queue) ----
    {
        const int t00 = (tg * TPB) * TT;
        if (doR) {
            int t = t00 - 10 + colR;
            bool ok = (t >= 0) && (t < TLEN);
            #pragma unroll
            for (int c = 0; c < 8; ++c)
                pkr[c] = (_Float16)(ok ? x[xr_base + (long)c * TLEN + t] : 0.f);
        }
        if (doI) {
            int t = t00 - 10 + colI;
            bool ok = (t >= 0) && (t < TLEN);
            #pragma unroll
            for (int c = 0; c < 8; ++c)
                pki[c] = (_Float16)(ok ? x[xi_base + (long)c * TLEN + t] : 0.f);
        }
    }

    // ---- a1 frags (latency hidden under X0 write + barrier) ----
    half8 a1[2][3];
    #pragma unroll
    for (int hr = 0; hr < 2; ++hr)
    #pragma unroll
    for (int p = 0; p < 3; ++p)
        a1[hr][p] = LOADFRAG(hr * 3 + p);

    // ---- write X0 ----
    if (doR) *(half8*)(sm + X0OFF + colR * (XSTRIDE * 2))      = pkr;
    if (doI) *(half8*)(sm + X0OFF + colI * (XSTRIDE * 2) + 16) = pki;
    __syncthreads();

    const int Xc = (r16 & 7) << 4;       // swizzle XOR ((col&7) == (r16&7))
    int woff64[2];                       // merged-epi byte offset: (mw*64+hr*32+g*8)^Xc
    #pragma unroll
    for (int hr = 0; hr < 2; ++hr)
        woff64[hr] = ((mw * 64 + hr * 32 + g * 8) ^ Xc);

    half8 a2[5][2][2];   // [w][hr][kk]
    half8 a3[5][2];      // [w][kk]

    #pragma unroll
    for (int i = 0; i < TPB; ++i) {
        const int  tl       = tg * TPB + i;
        const int  t0       = tl * TT;
        const bool interior = (tl >= 1) && (tl <= 14);
        const bool first    = (i == 0);
        const bool havenext = (i + 1 < TPB);
        char* Xb = sm + (i ? X1OFF : X0OFF);
        char* Xn = sm + (i ? X0OFF : X1OFF);

        // ---- issue next tile's x loads (land during L1+L2 compute) ----
        if (havenext) {
            const int t0n = t0 + TT;
            if (doR) {
                int t = t0n - 10 + colR;
                bool ok = (t >= 0) && (t < TLEN);
                #pragma unroll
                for (int c = 0; c < 8; ++c)
                    pkr[c] = (_Float16)(ok ? x[xr_base + (long)c * TLEN + t] : 0.f);
            }
            if (doI) {
                int t = t0n - 10 + colI;
                bool ok = (t >= 0) && (t < TLEN);
                #pragma unroll
                for (int c = 0; c < 8; ++c)
                    pki[c] = (_Float16)(ok ? x[xi_base + (long)c * TLEN + t] : 0.f);
            }
        }

        // ---- Phase L1: h1 = relu(cconv(x, W1)) over 144-col window ----
        {
            f32x4 acc[2][5] = {};

            if (first) {
                #pragma unroll
                for (int w = 0; w < 2; ++w)
                #pragma unroll
                for (int hr = 0; hr < 2; ++hr)
                #pragma unroll
                for (int kk = 0; kk < 2; ++kk)
                    a2[w][hr][kk] = LOADFRAG(6 + w * 4 + hr * 2 + kk);
            }

            const char* xb = Xb + ((nb0 * 16 + r16) * XSTRIDE + (g & 1) * 8) * 2;
            #pragma unroll
            for (int p = 0; p < 3; ++p) {
                int tap = 2 * p + (g >> 1);
                if (tap > 4) tap = 4;          // A is zero for these groups
                const char* xbp = xb + tap * (XSTRIDE * 2);
                #pragma unroll
                for (int nbi = 0; nbi < 5; ++nbi) {
                    if (nbi < nbn) {
                        const half8 bf = *(const half8*)(xbp + nbi * (16 * XSTRIDE * 2));
                        acc[0][nbi] = MFMA16(a1[0][p], bf, acc[0][nbi]);
                        acc[1][nbi] = MFMA16(a1[1][p], bf, acc[1][nbi]);
                    }
                }
            }

            if (first) {
                #pragma unroll
                for (int w = 2; w < 5; ++w)
                #pragma unroll
                for (int hr = 0; hr < 2; ++hr)
                #pragma unroll
                for (int kk = 0; kk < 2; ++kk)
                    a2[w][hr][kk] = LOADFRAG(6 + w * 4 + hr * 2 + kk);
            }

            // epilogue -> H1 (merged 8B writes)
            char* wb = sm + H1OFF + (nb0 * 16 + r16) * 128;
            #pragma unroll
            for (int nbi = 0; nbi < 5; ++nbi) {
                if (nbi < nbn) {
                    int t = t0 - 8 + nb0 * 16 + r16 + nbi * 16;
                    bool ok = interior || ((t >= 0) && (t < TLEN));
                    #pragma unroll
                    for (int hr = 0; hr < 2; ++hr) {
                        float v0 = ok ? fmaxf(acc[hr][nbi][0], 0.f) : 0.f;
                        float v1 = ok ? fmaxf(acc[hr][nbi][1], 0.f) : 0.f;
                        float v2 = ok ? fmaxf(acc[hr][nbi][2], 0.f) : 0.f;
                        float v3 = ok ? fmaxf(acc[hr][nbi][3], 0.f) : 0.f;
                        pk16x2 lo = __builtin_amdgcn_cvt_pkrtz(v0, v1);
                        pk16x2 hi = __builtin_amdgcn_cvt_pkrtz(v2, v3);
                        pk16x4 hv; hv[0] = lo[0]; hv[1] = lo[1]; hv[2] = hi[0]; hv[3] = hi[1];
                        *(pk16x4*)(wb + nbi * 2048 + woff64[hr]) = hv;
                    }
                }
            }
        }
        __syncthreads();

        // ---- Phase L2: h2 = relu(cconv(h1, W2)) over 144-col window ----
        {
            f32x4 acc[2][5] = {};
            #pragma unroll
            for (int w = 0; w < KW; ++w) {
                const int sc0 = nb0 * 16 + r16 + w - 2;
                const int vb  = sc0 * 128 + ((g * 16) ^ ((sc0 & 7) << 4));
                #pragma unroll
                for (int kk = 0; kk < 2; ++kk) {
                    const char* rb = sm + H1OFF + (kk ? (vb ^ 64) : vb);
                    #pragma unroll
                    for (int nbi = 0; nbi < 5; ++nbi) {
                        if (nbi < nbn) {
                            const half8 bf = *(const half8*)(rb + nbi * 2048);
                            acc[0][nbi] = MFMA16(a2[w][0][kk], bf, acc[0][nbi]);
                            acc[1][nbi] = MFMA16(a2[w][1][kk], bf, acc[1][nbi]);
                        }
                    }
                }
            }

            if (first) {
                #pragma unroll
                for (int w = 0; w < KW; ++w)
                #pragma unroll
                for (int kk = 0; kk < 2; ++kk)
                    a3[w][kk] = LOADFRAG(26 + w * 2 + kk);
            }

            char* wb = sm + H2OFF + (nb0 * 16 + r16) * 128;
            #pragma unroll
            for (int nbi = 0; nbi < 5; ++nbi) {
                if (nbi < nbn) {
                    int t = t0 - 8 + nb0 * 16 + r16 + nbi * 16;
                    bool ok = interior || ((t >= 0) && (t < TLEN));
                    #pragma unroll
                    for (int hr = 0; hr < 2; ++hr) {
                        float v0 = ok ? fmaxf(acc[hr][nbi][0], 0.f) : 0.f;
                        float v1 = ok ? fmaxf(acc[hr][nbi][1], 0.f) : 0.f;
                        float v2 = ok ? fmaxf(acc[hr][nbi][2], 0.f) : 0.f;
                        float v3 = ok ? fmaxf(acc[hr][nbi][3], 0.f) : 0.f;
                        pk16x2 lo = __builtin_amdgcn_cvt_pkrtz(v0, v1);
                        pk16x2 hi = __builtin_amdgcn_cvt_pkrtz(v2, v3);
                        pk16x4 hv; hv[0] = lo[0]; hv[1] = lo[1]; hv[2] = hi[0]; hv[3] = hi[1];
                        *(pk16x4*)(wb + nbi * 2048 + woff64[hr]) = hv;
                    }
                }
            }
        }
        __syncthreads();

        // ---- write next X buffer (loads issued at loop top have landed) ----
        if (havenext) {
            if (doR) *(half8*)(Xn + colR * (XSTRIDE * 2))      = pkr;
            if (doI) *(half8*)(Xn + colI * (XSTRIDE * 2) + 16) = pki;
        }

        // ---- Phase L3: h3 = cconv(h2, W3) (no relu), 128 cols; -> H1 region ----
        {
            f32x4 acc3[4] = {};
            #pragma unroll
            for (int w = 0; w < KW; ++w) {
                const int sc0 = nw * 64 + r16 + 6 + w;
                const int vb  = sc0 * 128 + ((g * 16) ^ ((sc0 & 7) << 4));
                #pragma unroll
                for (int kk = 0; kk < 2; ++kk) {
                    const char* rb = sm + H2OFF + (kk ? (vb ^ 64) : vb);
                    #pragma unroll
                    for (int nbi = 0; nbi < 4; ++nbi) {
                        const half8 bf = *(const half8*)(rb + nbi * 2048);
                        acc3[nbi] = MFMA16(a3[w][kk], bf, acc3[nbi]);
                    }
                }
            }
            char* wb3 = sm + H3OFF + (nw * 64 + r16) * (H3STRIDE * 2) + mw * 32 + g * 8;
            #pragma unroll
            for (int nbi = 0; nbi < 4; ++nbi) {
                pk16x2 lo = __builtin_amdgcn_cvt_pkrtz(acc3[nbi][0], acc3[nbi][1]);
                pk16x2 hi = __builtin_amdgcn_cvt_pkrtz(acc3[nbi][2], acc3[nbi][3]);
                pk16x4 hv; hv[0] = lo[0]; hv[1] = lo[1]; hv[2] = hi[0]; hv[3] = hi[1];
                *(pk16x4*)(wb3 + nbi * (16 * H3STRIDE * 2)) = hv;
            }
        }
        __syncthreads();

        // ---- Phase M: mask multiply + channel reduce + store ----
        {
            int s   = tid >> 7;         // 0..1
            int col = tid & 127;
            int t = t0 + col;
            if (t < TLEN) {
                const half8 xrv = *(const half8*)(Xb + ((col + 10) * XSTRIDE + 0) * 2);
                const half8 xiv = *(const half8*)(Xb + ((col + 10) * XSTRIDE + 8) * 2);
                half8 h3q[4];
                #pragma unroll
                for (int q = 0; q < 4; ++q)
                    h3q[q] = *(const half8*)(sm + H3OFF + col * (H3STRIDE * 2) + q * 16);
                float Yr = 0.f, Yi = 0.f;
                #pragma unroll
                for (int c = 0; c < NCH; ++c) {
                    float vr = (float)xrv[c];
                    float vi = (float)xiv[c];
                    int o = 2 * c + s;
                    float hr = (c < 4) ? (float)h3q[0][o] : (float)h3q[1][o - 8];
                    float hi = (c < 4) ? (float)h3q[2][o] : (float)h3q[3][o - 8];
                    Yr += vr * hr - vi * hi;
                    Yi += vr * hi + vi * hr;
                }
                out[((long)(b * 2 * F_BINS + f) * NSRC + s) * TLEN + t]          = Yr;
                out[((long)(b * 2 * F_BINS + F_BINS + f) * NSRC + s) * TLEN + t] = Yi;
            }
        }
        __syncthreads();
    }
}

extern "C" void kernel_launch(void* const* d_in, const int* in_sizes, int n_in,
                              void* d_out, int out_size, void* d_ws, size_t ws_size,
                              hipStream_t stream) {
    const float* x   = (const float*)d_in[0];
    const float* Wr1 = (const float*)d_in[1];
    const float* Wi1 = (const float*)d_in[2];
    const float* Wr2 = (const float*)d_in[3];
    const float* Wi2 = (const float*)d_in[4];
    const float* Wr3 = (const float*)d_in[5];
    const float* Wi3 = (const float*)d_in[6];
    float* out = (float*)d_out;

    dim3 block(256);
    dim3 grid(GRID);
    if (ws_size >= PW_BYTES) {
        _Float16* pw = (_Float16*)d_ws;
        repack_kernel<<<F_BINS * 4, block, 0, stream>>>(Wr1, Wi1, Wr2, Wi2, Wr3, Wi3, pw);
        cddcnn_mfma_kernel<true><<<grid, block, 0, stream>>>(
            x, Wr1, Wi1, Wr2, Wi2, Wr3, Wi3, out, pw);
    } else {
        cddcnn_mfma_kernel<false><<<grid, block, 0, stream>>>(
            x, Wr1, Wi1, Wr2, Wi2, Wr3, Wi3, out, nullptr);
    }
}

// Round 14
// 237.264 us; speedup vs baseline: 1.9820x; 1.9820x over previous
//
#include <hip/hip_runtime.h>

// ---------------- problem constants ----------------
#define F_BINS 257
#define NCH    8
#define NSRC   2
#define KW     5
#define HCH    32
#define TLEN   2000
#define BATCH  4

// ---------------- tiling ----------------
#define TT      128
#define NTILES  16          // 16*128 = 2048 >= 2000
#define NK      (BATCH * F_BINS)        // 1028 (b,f) pairs
#define NRANK   ((NK + 7) / 8)          // 129
#define GRID    (NRANK * NTILES * 8)    // 16512 (64 dead blocks)

// LDS layout (bytes): H1 at 0; X at 18432; H2 ALIASES X (X dead after L1 —
// phase M reads x from registers). h3 aliases H1 (dead after L2 reads).
#define XSTRIDE 24
#define XCOLS   148
#define HWIN    144                            // h1/h2 window: [t0-8, t0+136)
#define HSZ     (HWIN * 64 * 2)                // 18432 B
#define H1OFF   0
#define XOFF    HSZ                            // 18432
#define H2OFF   HSZ                            // aliases X
#define H3OFF   0                              // aliases H1
#define SMEM_BYTES (2 * HSZ)                   // 36864 B -> 4 blocks/CU
#define H3STRIDE 40                            // halves per col (32 used + pad)

// packed weight fragments: [f][frag*2+mw][lane] of half8 (16B each)
#define NFRAG   36
#define PW_HALF8_PER_F (NFRAG * 2 * 64)
#define PW_BYTES ((size_t)F_BINS * PW_HALF8_PER_F * 16)   // ~18.9 MB

typedef _Float16 half8  __attribute__((ext_vector_type(8)));
typedef __fp16   pk16x2 __attribute__((ext_vector_type(2)));   // cvt_pkrtz result type
typedef __fp16   pk16x4 __attribute__((ext_vector_type(4)));   // merged 8B epi store
typedef float    f32x4  __attribute__((ext_vector_type(4)));

#define MFMA16(a, b, c) __builtin_amdgcn_mfma_f32_16x16x32_f16(a, b, c, 0, 0, 0)

// frag ids: a1[hr][p] = hr*3+p (0..5); a2[w][hr][kk] = 6+w*4+hr*2+kk (6..25);
//           a3[w][kk] = 26+w*2+kk (26..35)
__device__ __forceinline__ half8 gather_frag(
    int f, int frag, int mw, int lane,
    const float* __restrict__ Wr1, const float* __restrict__ Wi1,
    const float* __restrict__ Wr2, const float* __restrict__ Wi2,
    const float* __restrict__ Wr3, const float* __restrict__ Wi3)
{
    const int g = lane >> 4, r16 = lane & 15;
    half8 v;
    if (frag < 6) {
        int hr = frag / 3, p = frag % 3;
        int tap = 2 * p + (g >> 1);
        #pragma unroll
        for (int j = 0; j < 8; ++j) {
            float val = 0.f;
            if (tap < KW) {
                long idx = (((long)f * HCH + hr * 16 + r16) * NCH + j) * KW + tap;
                if (mw == 0) val = (g & 1) ? -Wi1[idx] : Wr1[idx];
                else         val = (g & 1) ?  Wr1[idx] : Wi1[idx];
            }
            v[j] = (_Float16)val;
        }
    } else if (frag < 26) {
        int u = frag - 6;
        int w = u >> 2, hr = (u >> 1) & 1, kk = u & 1;
        #pragma unroll
        for (int j = 0; j < 8; ++j) {
            int c = g * 8 + j;
            long idx = (((long)f * HCH + hr * 16 + r16) * HCH + c) * KW + w;
            float val;
            if (mw == 0) val = kk ? -Wi2[idx] : Wr2[idx];
            else         val = kk ?  Wr2[idx] : Wi2[idx];
            v[j] = (_Float16)val;
        }
    } else {
        int u = frag - 26;
        int w = u >> 1, kk = u & 1;
        #pragma unroll
        for (int j = 0; j < 8; ++j) {
            int c = g * 8 + j;
            long idx = (((long)f * (NCH * NSRC) + r16) * HCH + c) * KW + w;
            float val;
            if (mw == 0) val = kk ? -Wi3[idx] : Wr3[idx];
            else         val = kk ?  Wr3[idx] : Wi3[idx];
            v[j] = (_Float16)val;
        }
    }
    return v;
}

__global__ __launch_bounds__(256) void repack_kernel(
    const float* __restrict__ Wr1, const float* __restrict__ Wi1,
    const float* __restrict__ Wr2, const float* __restrict__ Wi2,
    const float* __restrict__ Wr3, const float* __restrict__ Wi3,
    _Float16* __restrict__ pw)
{
    const int bid  = blockIdx.x;
    const int f    = bid >> 2;
    const int part = bid & 3;
    const int lane = threadIdx.x & 63;
    const int q    = threadIdx.x >> 6;
    half8* pwv = (half8*)pw;
    for (int u = part * 18 + q; u < part * 18 + 18; u += 4) {
        int frag = u >> 1, mw = u & 1;
        half8 v = gather_frag(f, frag, mw, lane, Wr1, Wi1, Wr2, Wi2, Wr3, Wi3);
        pwv[((size_t)f * (NFRAG * 2) + u) * 64 + lane] = v;
    }
}

template<bool PACKED>
__global__ __launch_bounds__(256, 4) void cddcnn_mfma_kernel(
    const float* __restrict__ x,
    const float* __restrict__ Wr1, const float* __restrict__ Wi1,
    const float* __restrict__ Wr2, const float* __restrict__ Wi2,
    const float* __restrict__ Wr3, const float* __restrict__ Wi3,
    float* __restrict__ out, const _Float16* __restrict__ pw)
{
    __shared__ __align__(16) char sm[SMEM_BYTES];

    const int tid  = threadIdx.x;
    const int lane = tid & 63;
    const int wv   = tid >> 6;
    const int mw   = wv >> 1;       // 0: real-out rows, 1: imag-out rows
    const int nw   = wv & 1;        // n-half
    const int g    = lane >> 4;
    const int r16  = lane & 15;

    // XCD swizzle: all 16 tiles of one k=(b,f) on xcd=k&7 (weights L2-resident)
    const int bid  = blockIdx.x;
    const int xcd  = bid & 7;
    const int rt   = bid >> 3;
    const int tl   = rt & 15;
    const int k    = ((rt >> 4) << 3) | xcd;
    if (k >= NK) return;
    const int f    = k % F_BINS;
    const int b    = k / F_BINS;
    const int t0   = tl * TT;
    const bool interior = (tl >= 1) && (tl <= 14);

    const int nb0 = nw ? 5 : 0;
    const int nbn = nw ? 4 : 5;

    const half8* pwf = PACKED ? ((const half8*)pw) + (size_t)f * PW_HALF8_PER_F + mw * 64 + lane
                              : nullptr;
    #define LOADFRAG(fr) (PACKED ? pwf[(fr) * 128] \
                                 : gather_frag(f, (fr), mw, lane, Wr1, Wi1, Wr2, Wi2, Wr3, Wi3))

    const long xr_base = ((long)(b * 2 * F_BINS + f) * NCH) * TLEN;
    const long xi_base = ((long)(b * 2 * F_BINS + F_BINS + f) * NCH) * TLEN;

    // ---- Phase X: stage x tile as fp16 [148 cols][16 ch] ----
    // thread-per-col: 16 coalesced loads -> 2x ds_write_b128 (conflict-free).
    // pkr/pki HELD in registers through phase M (8 VGPRs).
    half8 pkr = {}, pki = {};
    if (tid < XCOLS) {
        int t = t0 - 10 + tid;
        bool ok = (t >= 0) && (t < TLEN);
        #pragma unroll
        for (int c = 0; c < 8; ++c) {
            float vr = ok ? x[xr_base + (long)c * TLEN + t] : 0.f;
            float vi = ok ? x[xi_base + (long)c * TLEN + t] : 0.f;
            pkr[c] = (_Float16)vr;
            pki[c] = (_Float16)vi;
        }
        *(half8*)(sm + XOFF + tid * (XSTRIDE * 2))      = pkr;
        *(half8*)(sm + XOFF + tid * (XSTRIDE * 2) + 16) = pki;
    }

    // ---- a1 frags (latency hidden under staging + barrier) ----
    half8 a1[2][3];
    #pragma unroll
    for (int hr = 0; hr < 2; ++hr)
    #pragma unroll
    for (int p = 0; p < 3; ++p)
        a1[hr][p] = LOADFRAG(hr * 3 + p);
    __syncthreads();

    const int Xc = (r16 & 7) << 4;       // swizzle XOR ((col&7) == (r16&7))
    int woff64[2];                       // merged-epi byte offset: (mw*64+hr*32+g*8)^Xc
    #pragma unroll
    for (int hr = 0; hr < 2; ++hr)
        woff64[hr] = ((mw * 64 + hr * 32 + g * 8) ^ Xc);

    half8 a2n[2][2];     // rolling next-w frags [hr][kk]

    // ---- Phase L1: h1 = relu(cconv(x, W1)) over 144-col window ----
    {
        f32x4 acc[2][5] = {};
        const char* xb = sm + XOFF + ((nb0 * 16 + r16) * XSTRIDE + (g & 1) * 8) * 2;
        #pragma unroll
        for (int p = 0; p < 3; ++p) {
            int tap = 2 * p + (g >> 1);
            if (tap > 4) tap = 4;          // A is zero for these groups
            const char* xbp = xb + tap * (XSTRIDE * 2);
            #pragma unroll
            for (int nbi = 0; nbi < 5; ++nbi) {
                if (nbi < nbn) {
                    const half8 bf = *(const half8*)(xbp + nbi * (16 * XSTRIDE * 2));
                    acc[0][nbi] = MFMA16(a1[0][p], bf, acc[0][nbi]);
                    acc[1][nbi] = MFMA16(a1[1][p], bf, acc[1][nbi]);
                }
            }
        }

        // prefetch a2 for w=0 (hidden under epilogue + barrier)
        #pragma unroll
        for (int hr = 0; hr < 2; ++hr)
        #pragma unroll
        for (int kk = 0; kk < 2; ++kk)
            a2n[hr][kk] = LOADFRAG(6 + hr * 2 + kk);

        // epilogue -> H1 (merged 8B writes)
        char* wb = sm + H1OFF + (nb0 * 16 + r16) * 128;
        #pragma unroll
        for (int nbi = 0; nbi < 5; ++nbi) {
            if (nbi < nbn) {
                int t = t0 - 8 + nb0 * 16 + r16 + nbi * 16;
                bool ok = interior || ((t >= 0) && (t < TLEN));
                #pragma unroll
                for (int hr = 0; hr < 2; ++hr) {
                    float v0 = ok ? fmaxf(acc[hr][nbi][0], 0.f) : 0.f;
                    float v1 = ok ? fmaxf(acc[hr][nbi][1], 0.f) : 0.f;
                    float v2 = ok ? fmaxf(acc[hr][nbi][2], 0.f) : 0.f;
                    float v3 = ok ? fmaxf(acc[hr][nbi][3], 0.f) : 0.f;
                    pk16x2 lo = __builtin_amdgcn_cvt_pkrtz(v0, v1);
                    pk16x2 hi = __builtin_amdgcn_cvt_pkrtz(v2, v3);
                    pk16x4 hv; hv[0] = lo[0]; hv[1] = lo[1]; hv[2] = hi[0]; hv[3] = hi[1];
                    *(pk16x4*)(wb + nbi * 2048 + woff64[hr]) = hv;
                }
            }
        }
    }
    __syncthreads();

    // ---- Phase L2: h2 = relu(cconv(h1, W2)); write H2 (aliases dead X) ----
    {
        f32x4 acc[2][5] = {};
        #pragma unroll
        for (int w = 0; w < KW; ++w) {
            half8 a2c[2][2];
            #pragma unroll
            for (int hr = 0; hr < 2; ++hr)
            #pragma unroll
            for (int kk = 0; kk < 2; ++kk)
                a2c[hr][kk] = a2n[hr][kk];
            if (w < 4) {
                // rolling prefetch of w+1 frags (L2-hit, hidden under MFMAs)
                #pragma unroll
                for (int hr = 0; hr < 2; ++hr)
                #pragma unroll
                for (int kk = 0; kk < 2; ++kk)
                    a2n[hr][kk] = LOADFRAG(6 + (w + 1) * 4 + hr * 2 + kk);
            }

            const int sc0 = nb0 * 16 + r16 + w - 2;
            const int vb  = sc0 * 128 + ((g * 16) ^ ((sc0 & 7) << 4));
            #pragma unroll
            for (int kk = 0; kk < 2; ++kk) {
                const char* rb = sm + H1OFF + (kk ? (vb ^ 64) : vb);
                #pragma unroll
                for (int nbi = 0; nbi < 5; ++nbi) {
                    if (nbi < nbn) {
                        const half8 bf = *(const half8*)(rb + nbi * 2048);
                        acc[0][nbi] = MFMA16(a2c[0][kk], bf, acc[0][nbi]);
                        acc[1][nbi] = MFMA16(a2c[1][kk], bf, acc[1][nbi]);
                    }
                }
            }
        }

        // prefetch a3 for w=0 (reuse a2n storage shape: [0][kk])
        #pragma unroll
        for (int kk = 0; kk < 2; ++kk)
            a2n[0][kk] = LOADFRAG(26 + kk);

        char* wb = sm + H2OFF + (nb0 * 16 + r16) * 128;
        #pragma unroll
        for (int nbi = 0; nbi < 5; ++nbi) {
            if (nbi < nbn) {
                int t = t0 - 8 + nb0 * 16 + r16 + nbi * 16;
                bool ok = interior || ((t >= 0) && (t < TLEN));
                #pragma unroll
                for (int hr = 0; hr < 2; ++hr) {
                    float v0 = ok ? fmaxf(acc[hr][nbi][0], 0.f) : 0.f;
                    float v1 = ok ? fmaxf(acc[hr][nbi][1], 0.f) : 0.f;
                    float v2 = ok ? fmaxf(acc[hr][nbi][2], 0.f) : 0.f;
                    float v3 = ok ? fmaxf(acc[hr][nbi][3], 0.f) : 0.f;
                    pk16x2 lo = __builtin_amdgcn_cvt_pkrtz(v0, v1);
                    pk16x2 hi = __builtin_amdgcn_cvt_pkrtz(v2, v3);
                    pk16x4 hv; hv[0] = lo[0]; hv[1] = lo[1]; hv[2] = hi[0]; hv[3] = hi[1];
                    *(pk16x4*)(wb + nbi * 2048 + woff64[hr]) = hv;
                }
            }
        }
    }
    __syncthreads();

    // ---- Phase L3: h3 = cconv(h2, W3) (no relu), 128 cols; -> H1 region ----
    {
        f32x4 acc3[4] = {};
        #pragma unroll
        for (int w = 0; w < KW; ++w) {
            half8 a3c[2];
            #pragma unroll
            for (int kk = 0; kk < 2; ++kk)
                a3c[kk] = a2n[0][kk];
            if (w < 4) {
                #pragma unroll
                for (int kk = 0; kk < 2; ++kk)
                    a2n[0][kk] = LOADFRAG(26 + (w + 1) * 2 + kk);
            }

            const int sc0 = nw * 64 + r16 + 6 + w;
            const int vb  = sc0 * 128 + ((g * 16) ^ ((sc0 & 7) << 4));
            #pragma unroll
            for (int kk = 0; kk < 2; ++kk) {
                const char* rb = sm + H2OFF + (kk ? (vb ^ 64) : vb);
                #pragma unroll
                for (int nbi = 0; nbi < 4; ++nbi) {
                    const half8 bf = *(const half8*)(rb + nbi * 2048);
                    acc3[nbi] = MFMA16(a3c[kk], bf, acc3[nbi]);
                }
            }
        }
        char* wb3 = sm + H3OFF + (nw * 64 + r16) * (H3STRIDE * 2) + mw * 32 + g * 8;
        #pragma unroll
        for (int nbi = 0; nbi < 4; ++nbi) {
            pk16x2 lo = __builtin_amdgcn_cvt_pkrtz(acc3[nbi][0], acc3[nbi][1]);
            pk16x2 hi = __builtin_amdgcn_cvt_pkrtz(acc3[nbi][2], acc3[nbi][3]);
            pk16x4 hv; hv[0] = lo[0]; hv[1] = lo[1]; hv[2] = hi[0]; hv[3] = hi[1];
            *(pk16x4*)(wb3 + nbi * (16 * H3STRIDE * 2)) = hv;
        }
    }
    __syncthreads();

    // ---- Phase M: mask multiply + channel reduce + store ----
    // Thread tid (10..137) owns col = tid-10 (matches its staged pkr/pki).
    {
        int col = tid - 10;
        if (col >= 0 && col < TT) {
            int t = t0 + col;
            if (t < TLEN) {
                half8 h3q[4];
                #pragma unroll
                for (int q = 0; q < 4; ++q)
                    h3q[q] = *(const half8*)(sm + H3OFF + col * (H3STRIDE * 2) + q * 16);
                float Yr[2] = {0.f, 0.f}, Yi[2] = {0.f, 0.f};
                #pragma unroll
                for (int c = 0; c < NCH; ++c) {
                    float vr = (float)pkr[c];
                    float vi = (float)pki[c];
                    #pragma unroll
                    for (int s = 0; s < NSRC; ++s) {
                        int o = 2 * c + s;
                        float hr = (c < 4) ? (float)h3q[0][o] : (float)h3q[1][o - 8];
                        float hi = (c < 4) ? (float)h3q[2][o] : (float)h3q[3][o - 8];
                        Yr[s] += vr * hr - vi * hi;
                        Yi[s] += vr * hi + vi * hr;
                    }
                }
                #pragma unroll
                for (int s = 0; s < NSRC; ++s) {
                    out[((long)(b * 2 * F_BINS + f) * NSRC + s) * TLEN + t]          = Yr[s];
                    out[((long)(b * 2 * F_BINS + F_BINS + f) * NSRC + s) * TLEN + t] = Yi[s];
                }
            }
        }
    }
}

extern "C" void kernel_launch(void* const* d_in, const int* in_sizes, int n_in,
                              void* d_out, int out_size, void* d_ws, size_t ws_size,
                              hipStream_t stream) {
    const float* x   = (const float*)d_in[0];
    const float* Wr1 = (const float*)d_in[1];
    const float* Wi1 = (const float*)d_in[2];
    const float* Wr2 = (const float*)d_in[3];
    const float* Wi2 = (const float*)d_in[4];
    const float* Wr3 = (const float*)d_in[5];
    const float* Wi3 = (const float*)d_in[6];
    float* out = (float*)d_out;

    dim3 block(256);
    dim3 grid(GRID);
    if (ws_size >= PW_BYTES) {
        _Float16* pw = (_Float16*)d_ws;
        repack_kernel<<<F_BINS * 4, block, 0, stream>>>(Wr1, Wi1, Wr2, Wi2, Wr3, Wi3, pw);
        cddcnn_mfma_kernel<true><<<grid, block, 0, stream>>>(
            x, Wr1, Wi1, Wr2, Wi2, Wr3, Wi3, out, pw);
    } else {
        cddcnn_mfma_kernel<false><<<grid, block, 0, stream>>>(
            x, Wr1, Wi1, Wr2, Wi2, Wr3, Wi3, out, nullptr);
    }
}